// Round 4
// baseline (644.596 us; speedup 1.0000x reference)
//
#include <hip/hip_runtime.h>
#include <stdint.h>

#define NNODE 32768
#define NEDGE 524288
#define TDIM  512
#define CDIM  64
#define NBATCH 64
#define FC1N  256
#define FC2N  128
#define NCLSN 21

typedef __attribute__((ext_vector_type(8))) short short8;
typedef __attribute__((ext_vector_type(4))) float f32x4;

__device__ __forceinline__ unsigned short f2bf(float f){
  union { float f; unsigned u; } v; v.f = f;
  unsigned r = v.u + 0x7FFFu + ((v.u >> 16) & 1u);
  return (unsigned short)(r >> 16);
}

__device__ __forceinline__ void gload_lds16(const void* g, void* l){
  __builtin_amdgcn_global_load_lds(
      (const __attribute__((address_space(1))) uint32_t*)g,
      (__attribute__((address_space(3))) uint32_t*)l, 16, 0, 0);
}

// ---------------- normalization + CSR build ----------------

__global__ void k_init(float* deg, int* counts){
  int i = blockIdx.x*256 + threadIdx.x;
  deg[i] = 0.f; counts[i] = 0;
}

__global__ void k_degcount(const int* src, const int* dst, const float* w,
                           float* deg, int* counts){
  int e = blockIdx.x*256 + threadIdx.x;
  atomicAdd(&deg[src[e]], w[e]);
  atomicAdd(&counts[dst[e]], 1);
}

__global__ void k_dinv(const float* deg, float* dinv){
  int i = blockIdx.x*256 + threadIdx.x;
  float d = deg[i];
  dinv[i] = d > 0.f ? rsqrtf(d) : 0.f;
}

// one block, 1024 threads, 32 elements each -> exclusive scan of counts
__global__ void k_scan(const int* counts, int* row_ptr, int* wp){
  int t = threadIdx.x; int base = t*32;
  int local[32]; int s = 0;
#pragma unroll
  for(int i=0;i<32;i++){ local[i] = counts[base+i]; s += local[i]; }
  int lane = t & 63, w = t >> 6;
  int incl = s;
#pragma unroll
  for(int off=1; off<64; off<<=1){ int u = __shfl_up(incl, off); if(lane >= off) incl += u; }
  __shared__ int wsum[16];
  if(lane == 63) wsum[w] = incl;
  __syncthreads();
  if(w == 0){
    int v = (lane < 16) ? wsum[lane] : 0;
    int iv = v;
#pragma unroll
    for(int off=1; off<64; off<<=1){ int u = __shfl_up(iv, off); if(lane >= off) iv += u; }
    if(lane < 16) wsum[lane] = iv - v;
  }
  __syncthreads();
  int run = incl - s + wsum[w];
#pragma unroll
  for(int i=0;i<32;i++){ row_ptr[base+i] = run; wp[base+i] = run; run += local[i]; }
  if(t == 1023) row_ptr[NNODE] = run;
}

__global__ void k_scatter(const int* src, const int* dst, const float* w,
                          const float* dinv, int* wp, int* colA, float* valA){
  int e = blockIdx.x*256 + threadIdx.x;
  int s = src[e], d = dst[e];
  float nv = -dinv[s] * w[e] * dinv[d];
  int pos = atomicAdd(&wp[d], 1);
  colA[pos] = s; valA[pos] = nv;
}

// ---------------- conversions ----------------

__global__ void k_cvt(const float* in, unsigned short* out, int n8){
  int i = blockIdx.x*256 + threadIdx.x;
  if(i >= n8) return;
  const float4* p = (const float4*)(in + (size_t)i*8);
  float4 a = p[0], b = p[1];
  union { unsigned short u[8]; float4 v; } o;
  o.u[0]=f2bf(a.x); o.u[1]=f2bf(a.y); o.u[2]=f2bf(a.z); o.u[3]=f2bf(a.w);
  o.u[4]=f2bf(b.x); o.u[5]=f2bf(b.y); o.u[6]=f2bf(b.z); o.u[7]=f2bf(b.w);
  *(float4*)(out + (size_t)i*8) = o.v;
}

// W1 [5][512][64] fp32 -> Wt1 [320][512] bf16 (N-major, K contiguous)
__global__ void k_cvtW1(const float* W, unsigned short* Wt){
  int idx = blockIdx.x*256 + threadIdx.x;     // 320*512
  int j = idx >> 9, t = idx & 511;
  Wt[idx] = f2bf(W[(size_t)(j>>6)*(TDIM*CDIM) + (size_t)t*CDIM + (j&63)]);
}

// W2 [5][64][64] fp32 -> Wt2 [320][64] bf16
__global__ void k_cvtW2(const float* W, unsigned short* Wt){
  int idx = blockIdx.x*256 + threadIdx.x;     // 320*64
  int j = idx >> 6, t = idx & 63;
  Wt[idx] = f2bf(W[(size_t)(j>>6)*(CDIM*CDIM) + (size_t)t*CDIM + (j&63)]);
}

// ---------------- bf16 MFMA GEMM: [32768,Kdim] @ [Kdim,320] ----------------
// A: [M,Kdim] bf16 row-major; Bt: [320,Kdim] bf16; out Cout[5][32768][64] fp32
// Tile 128x64, BK=64, 4 waves (2x2), global_load_lds w/ XOR-swizzled LDS.

__global__ __launch_bounds__(256) void k_gemm2(const unsigned short* A, const unsigned short* Bt,
                                               float* Cout, int Kdim){
  __shared__ unsigned short As[128*64];   // [128 rows][128B], swizzled
  __shared__ unsigned short Bs[64*64];    // [64 rows][128B], swizzled
  int t = threadIdx.x, lane = t & 63, w = t >> 6;
  int m0 = blockIdx.x*128, n0 = blockIdx.y*64;
  int strideA = Kdim*2;

  const char* aSrc[4]; const char* bSrc[2];
#pragma unroll
  for(int c=0;c<4;c++){
    int o = c*4096 + t*16;
    int row = o >> 7;
    int cb = (o & 127) ^ ((row & 7) << 4);     // inverse swizzle on source
    aSrc[c] = (const char*)A + (size_t)(m0+row)*strideA + cb;
  }
#pragma unroll
  for(int c=0;c<2;c++){
    int o = c*4096 + t*16;
    int row = o >> 7;
    int cb = (o & 127) ^ ((row & 7) << 4);
    bSrc[c] = (const char*)Bt + (size_t)(n0+row)*strideA + cb;
  }

  int wm = w >> 1, wn = w & 1;
  f32x4 acc[4][2] = {};

  for(int k0 = 0; k0 < Kdim; k0 += 64){
#pragma unroll
    for(int c=0;c<4;c++) gload_lds16(aSrc[c] + k0*2, (char*)As + c*4096 + w*1024);
#pragma unroll
    for(int c=0;c<2;c++) gload_lds16(bSrc[c] + k0*2, (char*)Bs + c*4096 + w*1024);
    __syncthreads();

    short8 af[4][2], bf[2][2];
#pragma unroll
    for(int mf=0;mf<4;mf++){
      int r = wm*64 + mf*16 + (lane&15);
#pragma unroll
      for(int h=0;h<2;h++){
        int cb = (h*64 + ((lane>>4)*16)) ^ ((r & 7) << 4);
        af[mf][h] = *(const short8*)((const char*)As + r*128 + cb);
      }
    }
#pragma unroll
    for(int nf=0;nf<2;nf++){
      int r = wn*32 + nf*16 + (lane&15);
#pragma unroll
      for(int h=0;h<2;h++){
        int cb = (h*64 + ((lane>>4)*16)) ^ ((r & 7) << 4);
        bf[nf][h] = *(const short8*)((const char*)Bs + r*128 + cb);
      }
    }
#pragma unroll
    for(int h=0;h<2;h++)
#pragma unroll
      for(int mf=0;mf<4;mf++)
#pragma unroll
        for(int nf=0;nf<2;nf++)
          acc[mf][nf] = __builtin_amdgcn_mfma_f32_16x16x32_bf16(af[mf][h], bf[nf][h], acc[mf][nf], 0,0,0);
    __syncthreads();
  }

#pragma unroll
  for(int mf=0;mf<4;mf++)
#pragma unroll
    for(int nf=0;nf<2;nf++){
      int col = n0 + wn*32 + nf*16 + (lane & 15);
      int kk = col >> 6, cc = col & 63;
#pragma unroll
      for(int q=0;q<4;q++){
        int row = m0 + wm*64 + mf*16 + (lane>>4)*4 + q;
        Cout[(size_t)kk*NNODE*CDIM + (size_t)row*CDIM + cc] = acc[mf][nf][q];
      }
    }
}

// ---------------- fused Clenshaw SpMM step, LDS-staged sample window ----------------
// Block-diagonal graph: all gathers for nodes of sample s hit vin[s*512 .. s*512+511].
// 256 blocks x 512 threads; block stages its sample's 512x64 fp32 window (128 KB) in LDS,
// then 8 waves each process 16 nodes (lanes = 4 edge-slots x 16 channel-quads).

__global__ __launch_bounds__(512) void k_spmm2(const int* row_ptr, const int* colA, const float* valA,
    const float* vin, const float* addv, const float* subv, const float* bias,
    float scaleL, float* outf, unsigned short* outbf, int relu){
  __shared__ float win[512*CDIM];   // 131072 B
  int t = threadIdx.x;
  int sampleBase = (blockIdx.x >> 2) << 9;       // node-id base of this sample
  const float* vwin = vin + (size_t)sampleBase*CDIM;
#pragma unroll
  for(int i=0;i<16;i++){
    int idx = i*512 + t;                         // float4 index, 8192 total
    *(float4*)(&win[idx*4]) = *(const float4*)(vwin + (size_t)idx*4);
  }
  __syncthreads();
  int w = t >> 6, lane = t & 63;
  int eg = lane >> 4, ch = (lane & 15)*4;
  for(int i=0;i<16;i++){
    int node = blockIdx.x*128 + w*16 + i;
    int s = row_ptr[node], e = row_ptr[node+1];
    float4 acc = make_float4(0.f,0.f,0.f,0.f);
    for(int p = s; p < e; p += 4){
      int idx = p + eg;
      float v = 0.f; int c = sampleBase;
      if(idx < e){ c = colA[idx]; v = valA[idx]; }
      const float* vr = &win[(c - sampleBase)*CDIM + ch];
      float4 vv = *(const float4*)vr;
      acc.x += v*vv.x; acc.y += v*vv.y; acc.z += v*vv.z; acc.w += v*vv.w;
    }
#pragma unroll
    for(int m = 16; m <= 32; m <<= 1){
      acc.x += __shfl_xor(acc.x, m);
      acc.y += __shfl_xor(acc.y, m);
      acc.z += __shfl_xor(acc.z, m);
      acc.w += __shfl_xor(acc.w, m);
    }
    if(lane < 16){
      size_t off = (size_t)node*CDIM + ch;
      float4 av = *(const float4*)(addv + off);
      float4 r;
      r.x = scaleL*acc.x + av.x;
      r.y = scaleL*acc.y + av.y;
      r.z = scaleL*acc.z + av.z;
      r.w = scaleL*acc.w + av.w;
      if(subv){
        float4 sv = *(const float4*)(subv + off);
        r.x -= sv.x; r.y -= sv.y; r.z -= sv.z; r.w -= sv.w;
      }
      if(bias){
        float4 bv = *(const float4*)(bias + ch);
        r.x += bv.x; r.y += bv.y; r.z += bv.z; r.w += bv.w;
      }
      if(relu){
        r.x = fmaxf(r.x,0.f); r.y = fmaxf(r.y,0.f); r.z = fmaxf(r.z,0.f); r.w = fmaxf(r.w,0.f);
      }
      if(outf) *(float4*)(outf + off) = r;
      if(outbf){
        union { unsigned short u[4]; uint2 v; } o;
        o.u[0]=f2bf(r.x); o.u[1]=f2bf(r.y); o.u[2]=f2bf(r.z); o.u[3]=f2bf(r.w);
        *(uint2*)(outbf + off) = o.v;
      }
    }
  }
}

// ---------------- FC head ----------------

__global__ void k_fc1init(const float* fc1_b, float* out1){
  int i = blockIdx.x*256 + threadIdx.x;   // 64*256
  out1[i] = fc1_b[i & 255];
}

// split-K outer product: H=[64][32768], W=[32768][256]; 512 blocks x KC=64
// vector (f32x4) accumulators -> no scratch spill; 2 blocks/CU.
#define FC1_KC 64
__global__ __launch_bounds__(256) void k_fc1b(const float* S2, const float* W, float* partials){
  __shared__ float Hst[FC1_KC][68];          // transposed H tile
  int t = threadIdx.x;
  int ks = blockIdx.x * FC1_KC;
  for(int q = t; q < 64*FC1_KC; q += 256){
    int b = q >> 6;           // sample
    int k = q & 63;
    Hst[k][b] = S2[(size_t)b*32768 + ks + k];
  }
  __syncthreads();
  int tb = t >> 5, tj = t & 31;
  int b0 = tb*8, j0 = tj*8;
  f32x4 a0[8], a1[8];
#pragma unroll
  for(int i=0;i<8;i++){ a0[i] = (f32x4)0.f; a1[i] = (f32x4)0.f; }
  const float* Wp = W + (size_t)ks*256 + j0;
  for(int k = 0; k < FC1_KC; k++){
    f32x4 w0 = *(const f32x4*)(Wp);
    f32x4 w1 = *(const f32x4*)(Wp + 4);
    Wp += 256;
    f32x4 h0 = *(const f32x4*)(&Hst[k][b0]);
    f32x4 h1 = *(const f32x4*)(&Hst[k][b0+4]);
#pragma unroll
    for(int i=0;i<4;i++){
      a0[i]   += h0[i] * w0;  a1[i]   += h0[i] * w1;
      a0[i+4] += h1[i] * w0;  a1[i+4] += h1[i] * w1;
    }
  }
  float* P = partials + (size_t)blockIdx.x*16384;
#pragma unroll
  for(int i=0;i<8;i++){
    *(f32x4*)(P + (size_t)(b0+i)*256 + j0)     = a0[i];
    *(f32x4*)(P + (size_t)(b0+i)*256 + j0 + 4) = a1[i];
  }
}

__global__ void k_fc1red(const float* partials, float* out1){
  int i = blockIdx.x*256 + threadIdx.x;     // 16384 outputs
  int g0 = blockIdx.y*64;
  float acc = 0.f;
#pragma unroll 8
  for(int g = 0; g < 64; g++) acc += partials[(size_t)(g0+g)*16384 + i];
  atomicAdd(&out1[i], acc);
}

__global__ void k_fc23(const float* out1, const float* fc2_w, const float* fc2_b,
                       const float* fc3_w, const float* fc3_b, float* out){
  __shared__ float h1[256];
  __shared__ float h2[128];
  int b = blockIdx.x, t = threadIdx.x;  // 128 threads
  h1[t] = out1[(size_t)b*256 + t];
  h1[t+128] = out1[(size_t)b*256 + t + 128];
  __syncthreads();
  float a = fc2_b[t];
  for(int i=0;i<256;i++) a += h1[i] * fc2_w[(size_t)i*128 + t];
  h2[t] = a;
  __syncthreads();
  if(t < NCLSN){
    float o = fc3_b[t];
    for(int i=0;i<128;i++) o += h2[i] * fc3_w[(size_t)i*NCLSN + t];
    out[(size_t)b*NCLSN + t] = o;
  }
}

// ---------------- launch ----------------

extern "C" void kernel_launch(void* const* d_in, const int* in_sizes, int n_in,
                              void* d_out, int out_size, void* d_ws, size_t ws_size,
                              hipStream_t stream) {
  const float* x    = (const float*)d_in[0];
  const int*   ei   = (const int*)  d_in[1];
  const float* ew   = (const float*)d_in[2];
  const float* W1   = (const float*)d_in[3];
  const float* b1   = (const float*)d_in[4];
  const float* W2   = (const float*)d_in[5];
  const float* b2   = (const float*)d_in[6];
  const float* fc1w = (const float*)d_in[7];
  const float* fc1b = (const float*)d_in[8];
  const float* fc2w = (const float*)d_in[9];
  const float* fc2b = (const float*)d_in[10];
  const float* fc3w = (const float*)d_in[11];
  const float* fc3b = (const float*)d_in[12];
  const int* srcI = ei;
  const int* dstI = ei + NEDGE;
  float* outp = (float*)d_out;

  char* ws = (char*)d_ws;
  size_t o_xbf    = 0;                         // 33,554,432 (aliased later by b3/b2/b1/S2)
  size_t o_wt1    = o_xbf + 33554432;          // 327,680
  size_t o_wt2    = o_wt1 + 327680;            // 40,960
  size_t o_c      = o_wt2 + 40960;             // 41,943,040 (aliased later by partials)
  size_t o_hbf    = o_c + 41943040;            // 4,194,304
  size_t o_deg    = o_hbf + 4194304;
  size_t o_dinv   = o_deg + 131072;
  size_t o_counts = o_dinv + 131072;
  size_t o_rp     = o_counts + 131072;
  size_t o_wp     = o_rp + 131328;
  size_t o_col    = o_wp + 131072;
  size_t o_val    = o_col + 2097152;
  size_t o_out1   = o_val + 2097152;

  unsigned short* x_bf = (unsigned short*)(ws + o_xbf);
  unsigned short* Wt1  = (unsigned short*)(ws + o_wt1);
  unsigned short* Wt2  = (unsigned short*)(ws + o_wt2);
  float* cbuf  = (float*)(ws + o_c);
  unsigned short* h_bf = (unsigned short*)(ws + o_hbf);
  float* deg   = (float*)(ws + o_deg);
  float* dinv  = (float*)(ws + o_dinv);
  int*   counts= (int*)(ws + o_counts);
  int*   rp    = (int*)(ws + o_rp);
  int*   wp    = (int*)(ws + o_wp);
  int*   colA  = (int*)(ws + o_col);
  float* valA  = (float*)(ws + o_val);
  float* out1  = (float*)(ws + o_out1);

  float* b3buf = (float*)(ws + o_xbf);
  float* b2buf = (float*)(ws + o_xbf + 8388608);
  float* b1buf = (float*)(ws + o_xbf + 16777216);
  float* S2    = (float*)(ws + o_xbf + 25165824);
  float* partials = cbuf;   // 32 MB, cbuf dead by fc1 time

  float* c0 = cbuf;
  float* c1 = cbuf + 1*(size_t)NNODE*CDIM;
  float* c2 = cbuf + 2*(size_t)NNODE*CDIM;
  float* c3 = cbuf + 3*(size_t)NNODE*CDIM;
  float* c4 = cbuf + 4*(size_t)NNODE*CDIM;

  // normalization + CSR
  hipLaunchKernelGGL(k_init,     dim3(128),  dim3(256), 0, stream, deg, counts);
  hipLaunchKernelGGL(k_degcount, dim3(2048), dim3(256), 0, stream, srcI, dstI, ew, deg, counts);
  hipLaunchKernelGGL(k_dinv,     dim3(128),  dim3(256), 0, stream, deg, dinv);
  hipLaunchKernelGGL(k_scan,     dim3(1),    dim3(1024),0, stream, counts, rp, wp);
  hipLaunchKernelGGL(k_scatter,  dim3(2048), dim3(256), 0, stream, srcI, dstI, ew, dinv, wp, colA, valA);

  // conversions
  hipLaunchKernelGGL(k_cvt,   dim3(8192), dim3(256), 0, stream, x, x_bf, NNODE*TDIM/8);
  hipLaunchKernelGGL(k_cvtW1, dim3(640),  dim3(256), 0, stream, W1, Wt1);
  hipLaunchKernelGGL(k_cvtW2, dim3(80),   dim3(256), 0, stream, W2, Wt2);

  // layer 1: c_k = x @ W1[k]
  hipLaunchKernelGGL(k_gemm2, dim3(256,5), dim3(256), 0, stream, x_bf, Wt1, cbuf, TDIM);

  // layer 1 Clenshaw
  hipLaunchKernelGGL(k_spmm2, dim3(256), dim3(512), 0, stream, rp, colA, valA,
                     c4, c3, (const float*)nullptr, (const float*)nullptr, 2.f, b3buf, (unsigned short*)nullptr, 0);
  hipLaunchKernelGGL(k_spmm2, dim3(256), dim3(512), 0, stream, rp, colA, valA,
                     b3buf, c2, c4, (const float*)nullptr, 2.f, b2buf, (unsigned short*)nullptr, 0);
  hipLaunchKernelGGL(k_spmm2, dim3(256), dim3(512), 0, stream, rp, colA, valA,
                     b2buf, c1, b3buf, (const float*)nullptr, 2.f, b1buf, (unsigned short*)nullptr, 0);
  hipLaunchKernelGGL(k_spmm2, dim3(256), dim3(512), 0, stream, rp, colA, valA,
                     b1buf, c0, b2buf, b1, 1.f, (float*)nullptr, h_bf, 1);

  // layer 2: c_k = h @ W2[k]
  hipLaunchKernelGGL(k_gemm2, dim3(256,5), dim3(256), 0, stream, h_bf, Wt2, cbuf, CDIM);

  // layer 2 Clenshaw
  hipLaunchKernelGGL(k_spmm2, dim3(256), dim3(512), 0, stream, rp, colA, valA,
                     c4, c3, (const float*)nullptr, (const float*)nullptr, 2.f, b3buf, (unsigned short*)nullptr, 0);
  hipLaunchKernelGGL(k_spmm2, dim3(256), dim3(512), 0, stream, rp, colA, valA,
                     b3buf, c2, c4, (const float*)nullptr, 2.f, b2buf, (unsigned short*)nullptr, 0);
  hipLaunchKernelGGL(k_spmm2, dim3(256), dim3(512), 0, stream, rp, colA, valA,
                     b2buf, c1, b3buf, (const float*)nullptr, 2.f, b1buf, (unsigned short*)nullptr, 0);
  hipLaunchKernelGGL(k_spmm2, dim3(256), dim3(512), 0, stream, rp, colA, valA,
                     b1buf, c0, b2buf, b2, 1.f, S2, (unsigned short*)nullptr, 0);

  // FC head
  hipLaunchKernelGGL(k_fc1init, dim3(64), dim3(256), 0, stream, fc1b, out1);
  hipLaunchKernelGGL(k_fc1b, dim3(512), dim3(256), 0, stream, S2, fc1w, partials);
  hipLaunchKernelGGL(k_fc1red, dim3(64,8), dim3(256), 0, stream, partials, out1);
  hipLaunchKernelGGL(k_fc23, dim3(64), dim3(128), 0, stream, out1, fc2w, fc2b, fc3w, fc3b, outp);
}

// Round 5
// 384.880 us; speedup vs baseline: 1.6748x; 1.6748x over previous
//
#include <hip/hip_runtime.h>
#include <stdint.h>

#define NNODE 32768
#define NEDGE 524288
#define TDIM  512
#define CDIM  64
#define NBATCH 64
#define FC1N  256
#define FC2N  128
#define NCLSN 21

typedef __attribute__((ext_vector_type(8))) short short8;
typedef __attribute__((ext_vector_type(4))) float f32x4;

__device__ __forceinline__ unsigned short f2bf(float f){
  union { float f; unsigned u; } v; v.f = f;
  unsigned r = v.u + 0x7FFFu + ((v.u >> 16) & 1u);
  return (unsigned short)(r >> 16);
}

__device__ __forceinline__ void gload_lds16(const void* g, void* l){
  __builtin_amdgcn_global_load_lds(
      (const __attribute__((address_space(1))) uint32_t*)g,
      (__attribute__((address_space(3))) uint32_t*)l, 16, 0, 0);
}

// ---------------- normalization + CSR build ----------------

__global__ void k_init(float* deg, int* counts){
  int i = blockIdx.x*256 + threadIdx.x;
  deg[i] = 0.f; counts[i] = 0;
}

__global__ void k_degcount(const int* src, const int* dst, const float* w,
                           float* deg, int* counts){
  int e = blockIdx.x*256 + threadIdx.x;
  atomicAdd(&deg[src[e]], w[e]);
  atomicAdd(&counts[dst[e]], 1);
}

__global__ void k_dinv(const float* deg, float* dinv){
  int i = blockIdx.x*256 + threadIdx.x;
  float d = deg[i];
  dinv[i] = d > 0.f ? rsqrtf(d) : 0.f;
}

// one block, 1024 threads, 32 elements each -> exclusive scan of counts
__global__ void k_scan(const int* counts, int* row_ptr, int* wp){
  int t = threadIdx.x; int base = t*32;
  int local[32]; int s = 0;
#pragma unroll
  for(int i=0;i<32;i++){ local[i] = counts[base+i]; s += local[i]; }
  int lane = t & 63, w = t >> 6;
  int incl = s;
#pragma unroll
  for(int off=1; off<64; off<<=1){ int u = __shfl_up(incl, off); if(lane >= off) incl += u; }
  __shared__ int wsum[16];
  if(lane == 63) wsum[w] = incl;
  __syncthreads();
  if(w == 0){
    int v = (lane < 16) ? wsum[lane] : 0;
    int iv = v;
#pragma unroll
    for(int off=1; off<64; off<<=1){ int u = __shfl_up(iv, off); if(lane >= off) iv += u; }
    if(lane < 16) wsum[lane] = iv - v;
  }
  __syncthreads();
  int run = incl - s + wsum[w];
#pragma unroll
  for(int i=0;i<32;i++){ row_ptr[base+i] = run; wp[base+i] = run; run += local[i]; }
  if(t == 1023) row_ptr[NNODE] = run;
}

__global__ void k_scatter(const int* src, const int* dst, const float* w,
                          const float* dinv, int* wp, int* colA, float* valA){
  int e = blockIdx.x*256 + threadIdx.x;
  int s = src[e], d = dst[e];
  float nv = -dinv[s] * w[e] * dinv[d];
  int pos = atomicAdd(&wp[d], 1);
  colA[pos] = s; valA[pos] = nv;
}

// ---------------- conversions ----------------

__global__ void k_cvt(const float* in, unsigned short* out, int n8){
  int i = blockIdx.x*256 + threadIdx.x;
  if(i >= n8) return;
  const float4* p = (const float4*)(in + (size_t)i*8);
  float4 a = p[0], b = p[1];
  union { unsigned short u[8]; float4 v; } o;
  o.u[0]=f2bf(a.x); o.u[1]=f2bf(a.y); o.u[2]=f2bf(a.z); o.u[3]=f2bf(a.w);
  o.u[4]=f2bf(b.x); o.u[5]=f2bf(b.y); o.u[6]=f2bf(b.z); o.u[7]=f2bf(b.w);
  *(float4*)(out + (size_t)i*8) = o.v;
}

// W1 [5][512][64] fp32 -> Wt1 [320][512] bf16 (N-major, K contiguous)
__global__ void k_cvtW1(const float* W, unsigned short* Wt){
  int idx = blockIdx.x*256 + threadIdx.x;     // 320*512
  int j = idx >> 9, t = idx & 511;
  Wt[idx] = f2bf(W[(size_t)(j>>6)*(TDIM*CDIM) + (size_t)t*CDIM + (j&63)]);
}

// W2 [5][64][64] fp32 -> Wt2 [320][64] bf16
__global__ void k_cvtW2(const float* W, unsigned short* Wt){
  int idx = blockIdx.x*256 + threadIdx.x;     // 320*64
  int j = idx >> 6, t = idx & 63;
  Wt[idx] = f2bf(W[(size_t)(j>>6)*(CDIM*CDIM) + (size_t)t*CDIM + (j&63)]);
}

// ---------------- bf16 MFMA GEMM: [32768,Kdim] @ [Kdim,320] ----------------
// A: [M,Kdim] bf16 row-major; Bt: [320,Kdim] bf16; out Cout[5][32768][64] fp32
// Tile 128x64, BK=64, 4 waves (2x2), global_load_lds w/ XOR-swizzled LDS.

__global__ __launch_bounds__(256) void k_gemm2(const unsigned short* A, const unsigned short* Bt,
                                               float* Cout, int Kdim){
  __shared__ unsigned short As[128*64];   // [128 rows][128B], swizzled
  __shared__ unsigned short Bs[64*64];    // [64 rows][128B], swizzled
  int t = threadIdx.x, lane = t & 63, w = t >> 6;
  int m0 = blockIdx.x*128, n0 = blockIdx.y*64;
  int strideA = Kdim*2;

  const char* aSrc[4]; const char* bSrc[2];
#pragma unroll
  for(int c=0;c<4;c++){
    int o = c*4096 + t*16;
    int row = o >> 7;
    int cb = (o & 127) ^ ((row & 7) << 4);     // inverse swizzle on source
    aSrc[c] = (const char*)A + (size_t)(m0+row)*strideA + cb;
  }
#pragma unroll
  for(int c=0;c<2;c++){
    int o = c*4096 + t*16;
    int row = o >> 7;
    int cb = (o & 127) ^ ((row & 7) << 4);
    bSrc[c] = (const char*)Bt + (size_t)(n0+row)*strideA + cb;
  }

  int wm = w >> 1, wn = w & 1;
  f32x4 acc[4][2] = {};

  for(int k0 = 0; k0 < Kdim; k0 += 64){
#pragma unroll
    for(int c=0;c<4;c++) gload_lds16(aSrc[c] + k0*2, (char*)As + c*4096 + w*1024);
#pragma unroll
    for(int c=0;c<2;c++) gload_lds16(bSrc[c] + k0*2, (char*)Bs + c*4096 + w*1024);
    __syncthreads();

    short8 af[4][2], bf[2][2];
#pragma unroll
    for(int mf=0;mf<4;mf++){
      int r = wm*64 + mf*16 + (lane&15);
#pragma unroll
      for(int h=0;h<2;h++){
        int cb = (h*64 + ((lane>>4)*16)) ^ ((r & 7) << 4);
        af[mf][h] = *(const short8*)((const char*)As + r*128 + cb);
      }
    }
#pragma unroll
    for(int nf=0;nf<2;nf++){
      int r = wn*32 + nf*16 + (lane&15);
#pragma unroll
      for(int h=0;h<2;h++){
        int cb = (h*64 + ((lane>>4)*16)) ^ ((r & 7) << 4);
        bf[nf][h] = *(const short8*)((const char*)Bs + r*128 + cb);
      }
    }
#pragma unroll
    for(int h=0;h<2;h++)
#pragma unroll
      for(int mf=0;mf<4;mf++)
#pragma unroll
        for(int nf=0;nf<2;nf++)
          acc[mf][nf] = __builtin_amdgcn_mfma_f32_16x16x32_bf16(af[mf][h], bf[nf][h], acc[mf][nf], 0,0,0);
    __syncthreads();
  }

#pragma unroll
  for(int mf=0;mf<4;mf++)
#pragma unroll
    for(int nf=0;nf<2;nf++){
      int col = n0 + wn*32 + nf*16 + (lane & 15);
      int kk = col >> 6, cc = col & 63;
#pragma unroll
      for(int q=0;q<4;q++){
        int row = m0 + wm*64 + mf*16 + (lane>>4)*4 + q;
        Cout[(size_t)kk*NNODE*CDIM + (size_t)row*CDIM + cc] = acc[mf][nf][q];
      }
    }
}

// ---------------- fused per-layer Clenshaw kernel ----------------
// One launch per ChebConv layer. Block = (sample, 16-feature slice); 4 blocks/sample,
// 256 blocks total. Window b_cur [512 nodes][16 feats] fp32 lives in LDS across all
// 4 L-applications; adjacency (8192 edges/sample) staged once as float2{val,col}.
// Thread = (node, 8-feat half). b_prev / b_new in registers (stable ownership).
// Clenshaw: b3=2L c4+c3; b2=2L b3-c4+c2; b1=2L b2-b3+c1; out=L b1-b2+c0+bias (opt relu).

__global__ __launch_bounds__(1024) void k_cheb(const int* rp, const int* colA, const float* valA,
    const float* cbuf, const float* bias, float* outf, unsigned short* outbf, int relu){
  __shared__ float   win[512*16];   // 32 KB
  __shared__ float2  adj[8192];     // 64 KB: {val, col_local as int bits}
  __shared__ int     ls[513];       // 2 KB
  int t = threadIdx.x;
  int s   = blockIdx.x >> 2;
  int fs0 = (blockIdx.x & 3) * 16;
  int nodeBase = s << 9;
  int eBase = nodeBase * 16;        // s * 8192 (exactly 8192 edges per sample)

  for(int e = t; e < 8192; e += 1024)
    adj[e] = make_float2(valA[eBase + e], __int_as_float(colA[eBase + e] - nodeBase));
  if(t < 513) ls[t] = rp[nodeBase + t] - eBase;

  int n = t >> 1, half = t & 1;
  int fo = half * 8;
  size_t gofs = (size_t)(nodeBase + n)*CDIM + fs0 + fo;   // this thread's global elem base

  // win = c4 slice
  const float* c4 = cbuf + 4*(size_t)NNODE*CDIM;
  f32x4 w0 = *(const f32x4*)(c4 + gofs);
  f32x4 w1 = *(const f32x4*)(c4 + gofs + 4);
  *(f32x4*)&win[n*16 + fo]     = w0;
  *(f32x4*)&win[n*16 + fo + 4] = w1;
  f32x4 p0 = (f32x4)0.f, p1 = (f32x4)0.f;   // b_prev

  f32x4 bv0, bv1;
  if(bias){
    bv0 = *(const f32x4*)(bias + fs0 + fo);
    bv1 = *(const f32x4*)(bias + fs0 + fo + 4);
  } else { bv0 = (f32x4)0.f; bv1 = (f32x4)0.f; }

  __syncthreads();
  int es = ls[n], ee = ls[n+1];

  for(int step = 0; step < 4; step++){
    int k = 3 - step;
    float scale = (step < 3) ? 2.f : 1.f;
    const float* ck = cbuf + (size_t)k*NNODE*CDIM + gofs;
    f32x4 cv0 = *(const f32x4*)ck;
    f32x4 cv1 = *(const f32x4*)(ck + 4);

    f32x4 a0 = (f32x4)0.f, a1 = (f32x4)0.f;
    for(int e = es; e < ee; e++){
      float2 av = adj[e];
      int col = __float_as_int(av.y);
      const float* wr = &win[col*16 + fo];
      f32x4 v0 = *(const f32x4*)wr;
      f32x4 v1 = *(const f32x4*)(wr + 4);
      a0 += av.x * v0;
      a1 += av.x * v1;
    }
    __syncthreads();          // all gathers done before win overwrite

    f32x4 cur0 = *(f32x4*)&win[n*16 + fo];
    f32x4 cur1 = *(f32x4*)&win[n*16 + fo + 4];
    f32x4 nw0 = scale*a0 - p0 + cv0;
    f32x4 nw1 = scale*a1 - p1 + cv1;

    if(step < 3){
      *(f32x4*)&win[n*16 + fo]     = nw0;
      *(f32x4*)&win[n*16 + fo + 4] = nw1;
      p0 = cur0; p1 = cur1;
      __syncthreads();        // writes visible before next gather
    } else {
      nw0 += bv0; nw1 += bv1;
      if(relu){
#pragma unroll
        for(int i=0;i<4;i++){ nw0[i] = fmaxf(nw0[i],0.f); nw1[i] = fmaxf(nw1[i],0.f); }
      }
      if(outf){
        *(f32x4*)(outf + gofs)     = nw0;
        *(f32x4*)(outf + gofs + 4) = nw1;
      }
      if(outbf){
        union { unsigned short u[8]; uint4 v; } o;
#pragma unroll
        for(int i=0;i<4;i++){ o.u[i] = f2bf(nw0[i]); o.u[i+4] = f2bf(nw1[i]); }
        *(uint4*)(outbf + gofs) = o.v;
      }
    }
  }
}

// ---------------- FC head ----------------

__global__ void k_fc1init(const float* fc1_b, float* out1){
  int i = blockIdx.x*256 + threadIdx.x;   // 64*256
  out1[i] = fc1_b[i & 255];
}

// split-K outer product: H=[64][32768], W=[32768][256]; 512 blocks x KC=64
#define FC1_KC 64
__global__ __launch_bounds__(256) void k_fc1b(const float* S2, const float* W, float* partials){
  __shared__ float Hst[FC1_KC][68];          // transposed H tile
  int t = threadIdx.x;
  int ks = blockIdx.x * FC1_KC;
  for(int q = t; q < 64*FC1_KC; q += 256){
    int b = q >> 6;           // sample
    int k = q & 63;
    Hst[k][b] = S2[(size_t)b*32768 + ks + k];
  }
  __syncthreads();
  int tb = t >> 5, tj = t & 31;
  int b0 = tb*8, j0 = tj*8;
  f32x4 a0[8], a1[8];
#pragma unroll
  for(int i=0;i<8;i++){ a0[i] = (f32x4)0.f; a1[i] = (f32x4)0.f; }
  const float* Wp = W + (size_t)ks*256 + j0;
  for(int k = 0; k < FC1_KC; k++){
    f32x4 w0 = *(const f32x4*)(Wp);
    f32x4 w1 = *(const f32x4*)(Wp + 4);
    Wp += 256;
    f32x4 h0 = *(const f32x4*)(&Hst[k][b0]);
    f32x4 h1 = *(const f32x4*)(&Hst[k][b0+4]);
#pragma unroll
    for(int i=0;i<4;i++){
      a0[i]   += h0[i] * w0;  a1[i]   += h0[i] * w1;
      a0[i+4] += h1[i] * w0;  a1[i+4] += h1[i] * w1;
    }
  }
  float* P = partials + (size_t)blockIdx.x*16384;
#pragma unroll
  for(int i=0;i<8;i++){
    *(f32x4*)(P + (size_t)(b0+i)*256 + j0)     = a0[i];
    *(f32x4*)(P + (size_t)(b0+i)*256 + j0 + 4) = a1[i];
  }
}

__global__ void k_fc1red(const float* partials, float* out1){
  int i = blockIdx.x*256 + threadIdx.x;     // 16384 outputs
  int g0 = blockIdx.y*64;
  float acc = 0.f;
#pragma unroll 8
  for(int g = 0; g < 64; g++) acc += partials[(size_t)(g0+g)*16384 + i];
  atomicAdd(&out1[i], acc);
}

__global__ void k_fc23(const float* out1, const float* fc2_w, const float* fc2_b,
                       const float* fc3_w, const float* fc3_b, float* out){
  __shared__ float h1[256];
  __shared__ float h2[128];
  int b = blockIdx.x, t = threadIdx.x;  // 128 threads
  h1[t] = out1[(size_t)b*256 + t];
  h1[t+128] = out1[(size_t)b*256 + t + 128];
  __syncthreads();
  float a = fc2_b[t];
  for(int i=0;i<256;i++) a += h1[i] * fc2_w[(size_t)i*128 + t];
  h2[t] = a;
  __syncthreads();
  if(t < NCLSN){
    float o = fc3_b[t];
    for(int i=0;i<128;i++) o += h2[i] * fc3_w[(size_t)i*NCLSN + t];
    out[(size_t)b*NCLSN + t] = o;
  }
}

// ---------------- launch ----------------

extern "C" void kernel_launch(void* const* d_in, const int* in_sizes, int n_in,
                              void* d_out, int out_size, void* d_ws, size_t ws_size,
                              hipStream_t stream) {
  const float* x    = (const float*)d_in[0];
  const int*   ei   = (const int*)  d_in[1];
  const float* ew   = (const float*)d_in[2];
  const float* W1   = (const float*)d_in[3];
  const float* b1   = (const float*)d_in[4];
  const float* W2   = (const float*)d_in[5];
  const float* b2   = (const float*)d_in[6];
  const float* fc1w = (const float*)d_in[7];
  const float* fc1b = (const float*)d_in[8];
  const float* fc2w = (const float*)d_in[9];
  const float* fc2b = (const float*)d_in[10];
  const float* fc3w = (const float*)d_in[11];
  const float* fc3b = (const float*)d_in[12];
  const int* srcI = ei;
  const int* dstI = ei + NEDGE;
  float* outp = (float*)d_out;

  char* ws = (char*)d_ws;
  size_t o_xbf    = 0;                         // 33,554,432 (aliased later by S2)
  size_t o_wt1    = o_xbf + 33554432;          // 327,680
  size_t o_wt2    = o_wt1 + 327680;            // 40,960
  size_t o_c      = o_wt2 + 40960;             // 41,943,040 (aliased later by partials)
  size_t o_hbf    = o_c + 41943040;            // 4,194,304
  size_t o_deg    = o_hbf + 4194304;
  size_t o_dinv   = o_deg + 131072;
  size_t o_counts = o_dinv + 131072;
  size_t o_rp     = o_counts + 131072;
  size_t o_wp     = o_rp + 131328;
  size_t o_col    = o_wp + 131072;
  size_t o_val    = o_col + 2097152;
  size_t o_out1   = o_val + 2097152;

  unsigned short* x_bf = (unsigned short*)(ws + o_xbf);
  unsigned short* Wt1  = (unsigned short*)(ws + o_wt1);
  unsigned short* Wt2  = (unsigned short*)(ws + o_wt2);
  float* cbuf  = (float*)(ws + o_c);
  unsigned short* h_bf = (unsigned short*)(ws + o_hbf);
  float* deg   = (float*)(ws + o_deg);
  float* dinv  = (float*)(ws + o_dinv);
  int*   counts= (int*)(ws + o_counts);
  int*   rp    = (int*)(ws + o_rp);
  int*   wp    = (int*)(ws + o_wp);
  int*   colA  = (int*)(ws + o_col);
  float* valA  = (float*)(ws + o_val);
  float* out1  = (float*)(ws + o_out1);

  float* S2       = (float*)(ws + o_xbf);     // x_bf dead after gemm1
  float* partials = cbuf;                     // cbuf dead by fc1 time

  // normalization + CSR
  hipLaunchKernelGGL(k_init,     dim3(128),  dim3(256), 0, stream, deg, counts);
  hipLaunchKernelGGL(k_degcount, dim3(2048), dim3(256), 0, stream, srcI, dstI, ew, deg, counts);
  hipLaunchKernelGGL(k_dinv,     dim3(128),  dim3(256), 0, stream, deg, dinv);
  hipLaunchKernelGGL(k_scan,     dim3(1),    dim3(1024),0, stream, counts, rp, wp);
  hipLaunchKernelGGL(k_scatter,  dim3(2048), dim3(256), 0, stream, srcI, dstI, ew, dinv, wp, colA, valA);

  // conversions
  hipLaunchKernelGGL(k_cvt,   dim3(8192), dim3(256), 0, stream, x, x_bf, NNODE*TDIM/8);
  hipLaunchKernelGGL(k_cvtW1, dim3(640),  dim3(256), 0, stream, W1, Wt1);
  hipLaunchKernelGGL(k_cvtW2, dim3(80),   dim3(256), 0, stream, W2, Wt2);

  // layer 1: c_k = x @ W1[k], then fused Clenshaw -> h (bf16)
  hipLaunchKernelGGL(k_gemm2, dim3(256,5), dim3(256), 0, stream, x_bf, Wt1, cbuf, TDIM);
  hipLaunchKernelGGL(k_cheb,  dim3(256), dim3(1024), 0, stream, rp, colA, valA,
                     cbuf, b1, (float*)nullptr, h_bf, 1);

  // layer 2: c_k = h @ W2[k], then fused Clenshaw -> S2 (fp32)
  hipLaunchKernelGGL(k_gemm2, dim3(256,5), dim3(256), 0, stream, h_bf, Wt2, cbuf, CDIM);
  hipLaunchKernelGGL(k_cheb,  dim3(256), dim3(1024), 0, stream, rp, colA, valA,
                     cbuf, b2, S2, (unsigned short*)nullptr, 0);

  // FC head
  hipLaunchKernelGGL(k_fc1init, dim3(64), dim3(256), 0, stream, fc1b, out1);
  hipLaunchKernelGGL(k_fc1b, dim3(512), dim3(256), 0, stream, S2, fc1w, partials);
  hipLaunchKernelGGL(k_fc1red, dim3(64,8), dim3(256), 0, stream, partials, out1);
  hipLaunchKernelGGL(k_fc23, dim3(64), dim3(128), 0, stream, out1, fc2w, fc2b, fc3w, fc3b, outp);
}